// Round 1
// baseline (569.847 us; speedup 1.0000x reference)
//
#include <hip/hip_runtime.h>

// ---------------------------------------------------------------------------
// TopoTransform: batched sign-fixed QR (MGS) + per-site channel mix.
//   problem 0: B=32, C=64,  S=784   problem 1: B=32, C=256, S=196
//   out[b][c][s] = sum_k Q[s][c][k] * x[b][k][s],  Q[s] = qr(W[s]) sign-fixed
// MGS yields R[j][j] > 0 directly => Q already sign-fixed.
// ---------------------------------------------------------------------------

static constexpr int BB = 32;  // batch

// -------- transpose: in (R, S) row-major -> out (S, R) row-major ----------
__global__ __launch_bounds__(256) void tkern(const float* __restrict__ in,
                                             float* __restrict__ out,
                                             int R, int S) {
    __shared__ float tile[32][33];
    const int tx = threadIdx.x, ty = threadIdx.y;
    const int s0 = blockIdx.x * 32, r0 = blockIdx.y * 32;
    #pragma unroll
    for (int i = ty; i < 32; i += 8) {
        int r = r0 + i, s = s0 + tx;
        tile[i][tx] = (r < R && s < S) ? in[(size_t)r * S + s] : 0.f;
    }
    __syncthreads();
    #pragma unroll
    for (int i = ty; i < 32; i += 8) {
        int s = s0 + i, r = r0 + tx;
        if (s < S && r < R) out[(size_t)s * R + r] = tile[tx][i];
    }
}

// -------- fused register-resident MGS QR + apply ---------------------------
// Thread grid: RT=16 row-blocks x CT col-blocks (THREADS = 16*CT).
// t: rb = t&15 (16 consecutive lanes per column group -> shfl reductions),
//    cb = t>>4. Thread owns A[rb*TR + i][cb*4 + q], i<TR, q<4, in registers.
template<int C, int CT, int KC>
__global__ __launch_bounds__(16 * CT) void qr_apply(const float* __restrict__ W,
                                                    float* __restrict__ XY) {
    constexpr int RT = 16;
    constexpr int TR = C / RT;      // rows per thread
    constexpr int TC = C / CT;      // cols per thread
    static_assert(TC == 4, "col tile must be 4 (float4 paths)");
    constexpr int THREADS = RT * CT;
    constexpr int QSTR = TR + 4;    // padded q stride (2-way max on b128)
    constexpr int XSTR = C + 4;

    const int s  = blockIdx.x;
    const int t  = threadIdx.x;
    const int rb = t & 15;
    const int cb = t >> 4;

    __shared__ float qs[2][RT * QSTR];   // double-buffered q_j
    __shared__ float xs[BB * XSTR];      // X_s staged (B x C)
    __shared__ float qc[KC * C];         // Q chunk [kk][c], xor-swizzled

    // ---- load A tile (coalesced-ish float4 rows) ----
    float a[TR][4];
    {
        const float* Wp = W + (size_t)s * C * C + (size_t)(rb * TR) * C + cb * 4;
        #pragma unroll
        for (int i = 0; i < TR; ++i) {
            float4 v = *reinterpret_cast<const float4*>(Wp + (size_t)i * C);
            a[i][0] = v.x; a[i][1] = v.y; a[i][2] = v.z; a[i][3] = v.w;
        }
    }
    // ---- stage X_s into LDS ----
    {
        const float* Xp = XY + (size_t)s * BB * C;
        #pragma unroll
        for (int v = 0; v < (BB * C) / (4 * THREADS); ++v) {
            int idx = 4 * (t + v * THREADS);
            int b = idx / C, k = idx % C;
            float4 x4 = *reinterpret_cast<const float4*>(Xp + idx);
            *reinterpret_cast<float4*>(&xs[b * XSTR + k]) = x4;
        }
    }

    // ---- MGS: one barrier per iteration, reductions via shfl over 16 lanes
    int buf = 0;
    #pragma unroll 1
    for (int j = 0; j < C; ++j) {
        const int cbj = j >> 2, jj = j & 3;
        if (cb == cbj) {
            // static-index copies behind wave-uniform branch (rule #20)
            #pragma unroll
            for (int q = 0; q < 4; ++q) {
                if (q == jj) {
                    float p = 0.f;
                    #pragma unroll
                    for (int i = 0; i < TR; ++i) p += a[i][q] * a[i][q];
                    p += __shfl_xor(p, 1); p += __shfl_xor(p, 2);
                    p += __shfl_xor(p, 4); p += __shfl_xor(p, 8);
                    const float rn = 1.0f / sqrtf(p);
                    #pragma unroll
                    for (int i = 0; i < TR; ++i) a[i][q] *= rn;
                    #pragma unroll
                    for (int i = 0; i < TR; i += 4) {
                        *reinterpret_cast<float4*>(&qs[buf][rb * QSTR + i]) =
                            make_float4(a[i][q], a[i+1][q], a[i+2][q], a[i+3][q]);
                    }
                }
            }
        }
        __syncthreads();
        if (cb * 4 + 3 > j) {   // group-uniform guard: shfl lanes stay converged
            float qv[TR];
            #pragma unroll
            for (int i = 0; i < TR; i += 4) {
                float4 v = *reinterpret_cast<const float4*>(&qs[buf][rb * QSTR + i]);
                qv[i] = v.x; qv[i+1] = v.y; qv[i+2] = v.z; qv[i+3] = v.w;
            }
            #pragma unroll
            for (int q = 0; q < 4; ++q) {
                float p = 0.f;
                #pragma unroll
                for (int i = 0; i < TR; ++i) p += a[i][q] * qv[i];
                p += __shfl_xor(p, 1); p += __shfl_xor(p, 2);
                p += __shfl_xor(p, 4); p += __shfl_xor(p, 8);
                if (cb * 4 + q > j) {
                    #pragma unroll
                    for (int i = 0; i < TR; ++i) a[i][q] -= p * qv[i];
                }
            }
        }
        buf ^= 1;
    }

    // ---- apply: Y[b][c] = sum_k Q[c][k] * X[b][k], Q staged in k-chunks ----
    const int u  = t % (C / 4);   // output c-block (4 cols)
    const int bp = t / (C / 4);   // 0..15 -> b pair
    float acc[2][4] = {{0,0,0,0},{0,0,0,0}};

    #pragma unroll 1
    for (int ch = 0; ch < C / KC; ++ch) {
        __syncthreads();  // prev chunk consumed (and X staged for ch==0)
        if (cb >= (ch * KC) / 4 && cb < ((ch + 1) * KC) / 4) {
            #pragma unroll
            for (int q = 0; q < 4; ++q) {
                const int kk = cb * 4 + q - ch * KC;
                const int swz = (kk & 7) << 2;
                #pragma unroll
                for (int i = 0; i < TR; i += 4) {
                    const int cout = rb * TR + i;
                    *reinterpret_cast<float4*>(&qc[kk * C + (cout ^ swz)]) =
                        make_float4(a[i][q], a[i+1][q], a[i+2][q], a[i+3][q]);
                }
            }
        }
        __syncthreads();
        #pragma unroll
        for (int kk = 0; kk < KC; kk += 4) {
            const int k = ch * KC + kk;
            float4 x0 = *reinterpret_cast<const float4*>(&xs[(2*bp    ) * XSTR + k]);
            float4 x1 = *reinterpret_cast<const float4*>(&xs[(2*bp + 1) * XSTR + k]);
            #pragma unroll
            for (int m = 0; m < 4; ++m) {
                const int swz = ((kk + m) & 7) << 2;
                float4 qv4 = *reinterpret_cast<const float4*>(&qc[(kk + m) * C + ((4 * u) ^ swz)]);
                const float xa = (&x0.x)[m], xb = (&x1.x)[m];
                acc[0][0] += xa * qv4.x; acc[0][1] += xa * qv4.y;
                acc[0][2] += xa * qv4.z; acc[0][3] += xa * qv4.w;
                acc[1][0] += xb * qv4.x; acc[1][1] += xb * qv4.y;
                acc[1][2] += xb * qv4.z; acc[1][3] += xb * qv4.w;
            }
        }
    }
    // ---- write Y in place over X_s (coalesced float4) ----
    {
        float* Yp = XY + (size_t)s * BB * C;
        *reinterpret_cast<float4*>(Yp + (2*bp    ) * C + 4 * u) =
            make_float4(acc[0][0], acc[0][1], acc[0][2], acc[0][3]);
        *reinterpret_cast<float4*>(Yp + (2*bp + 1) * C + 4 * u) =
            make_float4(acc[1][0], acc[1][1], acc[1][2], acc[1][3]);
    }
}

extern "C" void kernel_launch(void* const* d_in, const int* in_sizes, int n_in,
                              void* d_out, int out_size, void* d_ws, size_t ws_size,
                              hipStream_t stream) {
    (void)in_sizes; (void)n_in; (void)out_size; (void)ws_size;
    const float* x0 = (const float*)d_in[0];  // (32, 64, 784)
    const float* x1 = (const float*)d_in[1];  // (32, 256, 196)
    const float* W0 = (const float*)d_in[2];  // (784, 64, 64)
    const float* W1 = (const float*)d_in[3];  // (196, 256, 256)
    float* y0  = (float*)d_out;               // (32, 64, 784) flat
    float* y1  = y0 + 1605632;                // (32, 256, 196) flat
    float* xt0 = (float*)d_ws;                // (784, 32*64)
    float* xt1 = xt0 + 1605632;               // (196, 32*256)

    dim3 tb(32, 8);
    // x (B*C, S) -> xt (S, B*C)
    tkern<<<dim3(25,  64), tb, 0, stream>>>(x0, xt0, 2048, 784);
    tkern<<<dim3(7,  256), tb, 0, stream>>>(x1, xt1, 8192, 196);
    // fused QR + apply (Y overwrites xt in place)
    qr_apply< 64, 16, 64><<<784,  256, 0, stream>>>(W0, xt0);
    qr_apply<256, 64, 16><<<196, 1024, 0, stream>>>(W1, xt1);
    // xt (S, B*C) -> y (B*C, S)
    tkern<<<dim3(64,  25), tb, 0, stream>>>(xt0, y0, 784, 2048);
    tkern<<<dim3(256,  7), tb, 0, stream>>>(xt1, y1, 196, 8192);
}

// Round 2
// 568.787 us; speedup vs baseline: 1.0019x; 1.0019x over previous
//
#include <hip/hip_runtime.h>

// ---------------------------------------------------------------------------
// TopoTransform: batched sign-fixed QR (MGS) + per-site channel mix.
//   problem 0: B=32, C=64,  S=784   problem 1: B=32, C=256, S=196
//   out[b][c][s] = sum_k Q[s][c][k] * x[b][k][s],  Q[s] = qr(W[s]) sign-fixed
// MGS yields R[j][j] > 0 directly => Q already sign-fixed.
//
// R2 change: __launch_bounds__(.., 4) — R1's C=256 dispatch got a 64-VGPR
// budget (compiler targeted 8 waves/EU) and spilled the 64-float register
// tile `a` to scratch (~26 GB L2 traffic, 533 us @ 25% VALUBusy). 4 waves/EU
// -> 128 VGPR budget -> tile stays in registers.
// ---------------------------------------------------------------------------

static constexpr int BB = 32;  // batch

// -------- transpose: in (R, S) row-major -> out (S, R) row-major ----------
__global__ __launch_bounds__(256) void tkern(const float* __restrict__ in,
                                             float* __restrict__ out,
                                             int R, int S) {
    __shared__ float tile[32][33];
    const int tx = threadIdx.x, ty = threadIdx.y;
    const int s0 = blockIdx.x * 32, r0 = blockIdx.y * 32;
    #pragma unroll
    for (int i = ty; i < 32; i += 8) {
        int r = r0 + i, s = s0 + tx;
        tile[i][tx] = (r < R && s < S) ? in[(size_t)r * S + s] : 0.f;
    }
    __syncthreads();
    #pragma unroll
    for (int i = ty; i < 32; i += 8) {
        int s = s0 + i, r = r0 + tx;
        if (s < S && r < R) out[(size_t)s * R + r] = tile[tx][i];
    }
}

// -------- fused register-resident MGS QR + apply ---------------------------
// Thread grid: RT=16 row-blocks x CT col-blocks (THREADS = 16*CT).
// t: rb = t&15 (16 consecutive lanes per column group -> shfl reductions),
//    cb = t>>4. Thread owns A[rb*TR + i][cb*4 + q], i<TR, q<4, in registers.
template<int C, int CT, int KC>
__global__ __launch_bounds__(16 * CT, 4) void qr_apply(const float* __restrict__ W,
                                                       float* __restrict__ XY) {
    constexpr int RT = 16;
    constexpr int TR = C / RT;      // rows per thread
    constexpr int TC = C / CT;      // cols per thread
    static_assert(TC == 4, "col tile must be 4 (float4 paths)");
    constexpr int THREADS = RT * CT;
    constexpr int QSTR = TR + 4;    // padded q stride
    constexpr int XSTR = C + 4;

    const int s  = blockIdx.x;
    const int t  = threadIdx.x;
    const int rb = t & 15;
    const int cb = t >> 4;

    __shared__ float qs[2][RT * QSTR];   // double-buffered q_j
    __shared__ float xs[BB * XSTR];      // X_s staged (B x C)
    __shared__ float qc[KC * C];         // Q chunk [kk][c], xor-swizzled

    // ---- load A tile (float4 rows) ----
    float a[TR][4];
    {
        const float* Wp = W + (size_t)s * C * C + (size_t)(rb * TR) * C + cb * 4;
        #pragma unroll
        for (int i = 0; i < TR; ++i) {
            float4 v = *reinterpret_cast<const float4*>(Wp + (size_t)i * C);
            a[i][0] = v.x; a[i][1] = v.y; a[i][2] = v.z; a[i][3] = v.w;
        }
    }
    // ---- stage X_s into LDS ----
    {
        const float* Xp = XY + (size_t)s * BB * C;
        #pragma unroll
        for (int v = 0; v < (BB * C) / (4 * THREADS); ++v) {
            int idx = 4 * (t + v * THREADS);
            int b = idx / C, k = idx % C;
            float4 x4 = *reinterpret_cast<const float4*>(Xp + idx);
            *reinterpret_cast<float4*>(&xs[b * XSTR + k]) = x4;
        }
    }

    // ---- MGS: one barrier per iteration, reductions via shfl over 16 lanes
    int buf = 0;
    #pragma unroll 1
    for (int j = 0; j < C; ++j) {
        const int cbj = j >> 2, jj = j & 3;
        if (cb == cbj) {
            // static-index copies behind wave-uniform branch (rule #20)
            #pragma unroll
            for (int q = 0; q < 4; ++q) {
                if (q == jj) {
                    float p = 0.f;
                    #pragma unroll
                    for (int i = 0; i < TR; ++i) p += a[i][q] * a[i][q];
                    p += __shfl_xor(p, 1); p += __shfl_xor(p, 2);
                    p += __shfl_xor(p, 4); p += __shfl_xor(p, 8);
                    const float rn = 1.0f / sqrtf(p);
                    #pragma unroll
                    for (int i = 0; i < TR; ++i) a[i][q] *= rn;
                    #pragma unroll
                    for (int i = 0; i < TR; i += 4) {
                        *reinterpret_cast<float4*>(&qs[buf][rb * QSTR + i]) =
                            make_float4(a[i][q], a[i+1][q], a[i+2][q], a[i+3][q]);
                    }
                }
            }
        }
        __syncthreads();
        if (cb * 4 + 3 > j) {   // group-uniform guard: shfl lanes stay converged
            float qv[TR];
            #pragma unroll
            for (int i = 0; i < TR; i += 4) {
                float4 v = *reinterpret_cast<const float4*>(&qs[buf][rb * QSTR + i]);
                qv[i] = v.x; qv[i+1] = v.y; qv[i+2] = v.z; qv[i+3] = v.w;
            }
            #pragma unroll
            for (int q = 0; q < 4; ++q) {
                float p = 0.f;
                #pragma unroll
                for (int i = 0; i < TR; ++i) p += a[i][q] * qv[i];
                p += __shfl_xor(p, 1); p += __shfl_xor(p, 2);
                p += __shfl_xor(p, 4); p += __shfl_xor(p, 8);
                if (cb * 4 + q > j) {
                    #pragma unroll
                    for (int i = 0; i < TR; ++i) a[i][q] -= p * qv[i];
                }
            }
        }
        buf ^= 1;
    }

    // ---- apply: Y[b][c] = sum_k Q[c][k] * X[b][k], Q staged in k-chunks ----
    const int u  = t % (C / 4);   // output c-block (4 cols)
    const int bp = t / (C / 4);   // 0..15 -> b pair
    float acc[2][4] = {{0,0,0,0},{0,0,0,0}};

    #pragma unroll 1
    for (int ch = 0; ch < C / KC; ++ch) {
        __syncthreads();  // prev chunk consumed (and X staged for ch==0)
        if (cb >= (ch * KC) / 4 && cb < ((ch + 1) * KC) / 4) {
            #pragma unroll
            for (int q = 0; q < 4; ++q) {
                const int kk = cb * 4 + q - ch * KC;
                const int swz = (kk & 7) << 2;
                #pragma unroll
                for (int i = 0; i < TR; i += 4) {
                    const int cout = rb * TR + i;
                    *reinterpret_cast<float4*>(&qc[kk * C + (cout ^ swz)]) =
                        make_float4(a[i][q], a[i+1][q], a[i+2][q], a[i+3][q]);
                }
            }
        }
        __syncthreads();
        #pragma unroll
        for (int kk = 0; kk < KC; kk += 4) {
            const int k = ch * KC + kk;
            float4 x0 = *reinterpret_cast<const float4*>(&xs[(2*bp    ) * XSTR + k]);
            float4 x1 = *reinterpret_cast<const float4*>(&xs[(2*bp + 1) * XSTR + k]);
            #pragma unroll
            for (int m = 0; m < 4; ++m) {
                const int swz = ((kk + m) & 7) << 2;
                float4 qv4 = *reinterpret_cast<const float4*>(&qc[(kk + m) * C + ((4 * u) ^ swz)]);
                const float xa = (&x0.x)[m], xb = (&x1.x)[m];
                acc[0][0] += xa * qv4.x; acc[0][1] += xa * qv4.y;
                acc[0][2] += xa * qv4.z; acc[0][3] += xa * qv4.w;
                acc[1][0] += xb * qv4.x; acc[1][1] += xb * qv4.y;
                acc[1][2] += xb * qv4.z; acc[1][3] += xb * qv4.w;
            }
        }
    }
    // ---- write Y in place over X_s (coalesced float4) ----
    {
        float* Yp = XY + (size_t)s * BB * C;
        *reinterpret_cast<float4*>(Yp + (2*bp    ) * C + 4 * u) =
            make_float4(acc[0][0], acc[0][1], acc[0][2], acc[0][3]);
        *reinterpret_cast<float4*>(Yp + (2*bp + 1) * C + 4 * u) =
            make_float4(acc[1][0], acc[1][1], acc[1][2], acc[1][3]);
    }
}

extern "C" void kernel_launch(void* const* d_in, const int* in_sizes, int n_in,
                              void* d_out, int out_size, void* d_ws, size_t ws_size,
                              hipStream_t stream) {
    (void)in_sizes; (void)n_in; (void)out_size; (void)ws_size;
    const float* x0 = (const float*)d_in[0];  // (32, 64, 784)
    const float* x1 = (const float*)d_in[1];  // (32, 256, 196)
    const float* W0 = (const float*)d_in[2];  // (784, 64, 64)
    const float* W1 = (const float*)d_in[3];  // (196, 256, 256)
    float* y0  = (float*)d_out;               // (32, 64, 784) flat
    float* y1  = y0 + 1605632;                // (32, 256, 196) flat
    float* xt0 = (float*)d_ws;                // (784, 32*64)
    float* xt1 = xt0 + 1605632;               // (196, 32*256)

    dim3 tb(32, 8);
    // x (B*C, S) -> xt (S, B*C)
    tkern<<<dim3(25,  64), tb, 0, stream>>>(x0, xt0, 2048, 784);
    tkern<<<dim3(7,  256), tb, 0, stream>>>(x1, xt1, 8192, 196);
    // fused QR + apply (Y overwrites xt in place)
    qr_apply< 64, 16, 64><<<784,  256, 0, stream>>>(W0, xt0);
    qr_apply<256, 64, 16><<<196, 1024, 0, stream>>>(W1, xt1);
    // xt (S, B*C) -> y (B*C, S)
    tkern<<<dim3(64,  25), tb, 0, stream>>>(xt0, y0, 784, 2048);
    tkern<<<dim3(256,  7), tb, 0, stream>>>(xt1, y1, 196, 8192);
}